// Round 17
// baseline (161.598 us; speedup 1.0000x reference)
//
#include <hip/hip_runtime.h>

#define BB 2
#define LL 2048
#define DD 1024
#define HH 16
#define DHH 64

typedef _Float16 f16;
typedef _Float16 f16x8 __attribute__((ext_vector_type(8)));
typedef _Float16 f16x4 __attribute__((ext_vector_type(4)));
typedef _Float16 f16x2 __attribute__((ext_vector_type(2)));
typedef float f32x4 __attribute__((ext_vector_type(4)));
typedef unsigned long long u64;

#define VWAIT(N) asm volatile("s_waitcnt vmcnt(" #N ")" ::: "memory")
#define LWAIT0() asm volatile("s_waitcnt lgkmcnt(0)" ::: "memory")
#define SB0() __builtin_amdgcn_sched_barrier(0)

__device__ __forceinline__ void gload_lds16(const void* g, void* l) {
    __builtin_amdgcn_global_load_lds(
        (const __attribute__((address_space(1))) void*)g,
        (__attribute__((address_space(3))) void*)l, 16, 0, 0);
}

__device__ __forceinline__ f16x4 cvt4f(float4 v) {
    f16x4 o;
    o[0] = (f16)v.x; o[1] = (f16)v.y; o[2] = (f16)v.z; o[3] = (f16)v.w;
    return o;
}

__device__ __forceinline__ f16x8 cvt8f(float4 a, float4 b) {
    f16x2 p0 = __builtin_bit_cast(f16x2, __builtin_amdgcn_cvt_pkrtz(a.x, a.y));
    f16x2 p1 = __builtin_bit_cast(f16x2, __builtin_amdgcn_cvt_pkrtz(a.z, a.w));
    f16x2 p2 = __builtin_bit_cast(f16x2, __builtin_amdgcn_cvt_pkrtz(b.x, b.y));
    f16x2 p3 = __builtin_bit_cast(f16x2, __builtin_amdgcn_cvt_pkrtz(b.z, b.w));
    f16x8 r;
    r[0] = p0[0]; r[1] = p0[1]; r[2] = p1[0]; r[3] = p1[1];
    r[4] = p2[0]; r[5] = p2[1]; r[6] = p3[0]; r[7] = p3[1];
    return r;
}

// ---------------- prep: weight conversion only (mask pack fused into gemm_qkv) ----------------
__global__ void prep_w(const float* __restrict__ wq, const float* __restrict__ wk,
                       const float* __restrict__ wv, const float* __restrict__ wo,
                       f16* __restrict__ wh) {
    int i = blockIdx.x * 256 + threadIdx.x;
    const int stride = 1024 * 256;
    for (; i < 4 * 262144; i += stride) {
        const int sel = i >> 18, j = i & 262143;
        const float* s = sel == 0 ? wq : sel == 1 ? wk : sel == 2 ? wv : wo;
        ((f16x4*)wh)[i] = cvt4f(((const float4*)s)[j]);
    }
}

// standalone pieces for the fallback path
__global__ void cvt_kernel(const float* __restrict__ src, f16* __restrict__ dst, int n4, float sc) {
    int i = blockIdx.x * blockDim.x + threadIdx.x;
    const int stride = gridDim.x * blockDim.x;
    for (; i < n4; i += stride) {
        float4 v = ((const float4*)src)[i];
        v.x *= sc; v.y *= sc; v.z *= sc; v.w *= sc;
        ((f16x4*)dst)[i] = cvt4f(v);
    }
}
__global__ void cvt4_kernel(const float* __restrict__ a, const float* __restrict__ b,
                            const float* __restrict__ c, const float* __restrict__ d,
                            f16* __restrict__ dst, int n4) {
    const float* s = blockIdx.y == 0 ? a : blockIdx.y == 1 ? b : blockIdx.y == 2 ? c : d;
    f16* o = dst + (size_t)blockIdx.y * n4 * 4;
    int i = blockIdx.x * blockDim.x + threadIdx.x;
    const int stride = gridDim.x * blockDim.x;
    for (; i < n4; i += stride)
        ((f16x4*)o)[i] = cvt4f(((const float4*)s)[i]);
}
__global__ void pack_mask(const int* __restrict__ mask, u64* __restrict__ out, int nwords) {
    const int lane = threadIdx.x & 63;
    int w = (blockIdx.x * blockDim.x + threadIdx.x) >> 6;
    const int nw = (gridDim.x * blockDim.x) >> 6;
    for (; w < nwords; w += nw) {
        int mv = mask[(size_t)w * 64 + lane];
        u64 bits = __ballot(mv != 0);
        if (lane == 0) {
            const int kt = w & 31;
            const int bq = w >> 5;
            const int qq = bq & 2047, b = bq >> 11;
            out[((size_t)b * 32 + kt) * LL + qq] = bits;
        }
    }
}

// ---------------- fused QKV projection GEMM (R9) + ILP-4 mask pack ----------------
// Blocks 0..127: mask pack with 4 independent loads per round (64 rounds x ~600cy ~= 16us,
// hidden under the ~75us latency-bound GEMM; R14's failure was a 256-deep SERIAL chain).
// Blocks 128..895: R9's fused-cvt GEMM verbatim (A f32 reg-staged, W f16 global_load_lds,
// depth-1 A lead / depth-2 W lead, VWAIT(2), XCD-swizzled).
__global__ __launch_bounds__(256) void gemm_qkv(
        const float* __restrict__ A0, const float* __restrict__ A1, const float* __restrict__ A2,
        const f16* __restrict__ W0, const f16* __restrict__ W1, const f16* __restrict__ W2,
        f16* __restrict__ C0, f16* __restrict__ C1, f16* __restrict__ C2, float scq,
        const int* __restrict__ msk, u64* __restrict__ Mp) {
    __shared__ __align__(16) char lds[49152];
    const int tid = threadIdx.x;
    if (blockIdx.x < 128) {
        const int lane = tid & 63;
        const int wave = (blockIdx.x * 256 + tid) >> 6;   // 0..511
        const int nw = 512;
        // NMW = 131072 = 4*512*64 exactly: all four words valid every round
        for (int w0 = wave; w0 < BB * LL * 32; w0 += 4 * nw) {
            const int w1 = w0 + nw, w2 = w0 + 2 * nw, w3 = w0 + 3 * nw;
            const int mv0 = msk[(size_t)w0 * 64 + lane];
            const int mv1 = msk[(size_t)w1 * 64 + lane];
            const int mv2 = msk[(size_t)w2 * 64 + lane];
            const int mv3 = msk[(size_t)w3 * 64 + lane];
            const u64 b0 = __ballot(mv0 != 0);
            const u64 b1 = __ballot(mv1 != 0);
            const u64 b2 = __ballot(mv2 != 0);
            const u64 b3 = __ballot(mv3 != 0);
            if (lane == 0) {
                #define STW(W, B) { const int kt = (W) & 31; const int bq = (W) >> 5;          \
                                    const int qq = bq & 2047, bb = bq >> 11;                   \
                                    Mp[((size_t)bb * 32 + kt) * LL + qq] = (B); }
                STW(w0, b0); STW(w1, b1); STW(w2, b2); STW(w3, b3);
                #undef STW
            }
        }
        return;
    }
    const int bid = blockIdx.x - 128;
    const int xcd = bid & 7, j = bid >> 3;      // j 0..95
    const int p = xcd * 12 + (j >> 3);          // A-panel index 0..95
    const int xb = j & 7;
    const int z = p >> 5, yb = p & 31;
    const float* __restrict__ A = z == 0 ? A0 : z == 1 ? A1 : A2;
    const f16* __restrict__ W = z == 0 ? W0 : z == 1 ? W1 : W2;
    f16* __restrict__ C       = z == 0 ? C0 : z == 1 ? C1 : C2;

    const int wid = tid >> 6, lane = tid & 63;
    const int m0 = yb * 128, n0 = xb * 128;
    const int lq = lane & 15, lg = lane >> 4;
    const int wm = (wid >> 1) << 6, wn = (wid & 1) << 6;
    const int ar0 = (wid * 2) * 16 + (lane >> 2);
    const int ar1 = (wid * 2 + 1) * 16 + (lane >> 2);
    const int ac8 = lane & 3;
    const float* a0p = A + (size_t)(m0 + ar0) * DD + ac8 * 8;
    const float* a1p = A + (size_t)(m0 + ar1) * DD + ac8 * 8;
    char* aw0 = lds + ar0 * 64 + ac8 * 16;
    char* aw1 = lds + ar1 * 64 + ac8 * 16;

    f32x4 acc[4][4] = {};
    float4 arA[2][2], arB[2][2];

    // ---- prologue: write A(0),A(1) to LDS; load A(2)->arA; issue W(0),W(1) ----
    {
        float4 t00 = *(const float4*)(a0p + 0 * 32);
        float4 t01 = *(const float4*)(a0p + 0 * 32 + 4);
        float4 t10 = *(const float4*)(a1p + 0 * 32);
        float4 t11 = *(const float4*)(a1p + 0 * 32 + 4);
        VWAIT(0);
        *(f16x8*)(aw0 + 0 * 8192) = cvt8f(t00, t01);
        *(f16x8*)(aw1 + 0 * 8192) = cvt8f(t10, t11);
        t00 = *(const float4*)(a0p + 1 * 32);
        t01 = *(const float4*)(a0p + 1 * 32 + 4);
        t10 = *(const float4*)(a1p + 1 * 32);
        t11 = *(const float4*)(a1p + 1 * 32 + 4);
        VWAIT(0);
        *(f16x8*)(aw0 + 1 * 8192) = cvt8f(t00, t01);
        *(f16x8*)(aw1 + 1 * 8192) = cvt8f(t10, t11);
        SB0();
        arA[0][0] = *(const float4*)(a0p + 2 * 32);
        arA[0][1] = *(const float4*)(a0p + 2 * 32 + 4);
        arA[1][0] = *(const float4*)(a1p + 2 * 32);
        arA[1][1] = *(const float4*)(a1p + 2 * 32 + 4);
        SB0();
        #pragma unroll
        for (int t = 0; t < 2; ++t)
            #pragma unroll
            for (int jj = 0; jj < 2; ++jj) {
                const int ldsoff = (wid * 2 + jj) << 10;
                const int o = ldsoff + lane * 16;
                const int row = o >> 6, c8 = (o >> 4) & 3;
                gload_lds16(W + (size_t)(n0 + row) * DD + t * 32 + c8 * 8,
                            lds + 24576 + t * 8192 + ldsoff);
            }
        LWAIT0();
    }

    #pragma unroll
    for (int kt = 0; kt < 32; ++kt) {
        VWAIT(2);
        SB0();
        __builtin_amdgcn_s_barrier();
        SB0();
        {
            const int wb = (kt + 2) % 3;
            const int nk = (kt + 3 < 32) ? kt + 3 : 31;
            if ((kt & 1) == 0) {
                *(f16x8*)(aw0 + wb * 8192) = cvt8f(arA[0][0], arA[0][1]);
                *(f16x8*)(aw1 + wb * 8192) = cvt8f(arA[1][0], arA[1][1]);
                SB0();
                arB[0][0] = *(const float4*)(a0p + nk * 32);
                arB[0][1] = *(const float4*)(a0p + nk * 32 + 4);
                arB[1][0] = *(const float4*)(a1p + nk * 32);
                arB[1][1] = *(const float4*)(a1p + nk * 32 + 4);
            } else {
                *(f16x8*)(aw0 + wb * 8192) = cvt8f(arB[0][0], arB[0][1]);
                *(f16x8*)(aw1 + wb * 8192) = cvt8f(arB[1][0], arB[1][1]);
                SB0();
                arA[0][0] = *(const float4*)(a0p + nk * 32);
                arA[0][1] = *(const float4*)(a0p + nk * 32 + 4);
                arA[1][0] = *(const float4*)(a1p + nk * 32);
                arA[1][1] = *(const float4*)(a1p + nk * 32 + 4);
            }
        }
        SB0();
        {
            const int nk = (kt + 2 < 32) ? kt + 2 : 31;
            const int nb = (kt + 2) % 3;
            #pragma unroll
            for (int jj = 0; jj < 2; ++jj) {
                const int ldsoff = (wid * 2 + jj) << 10;
                const int o = ldsoff + lane * 16;
                const int row = o >> 6, c8 = (o >> 4) & 3;
                gload_lds16(W + (size_t)(n0 + row) * DD + nk * 32 + c8 * 8,
                            lds + 24576 + nb * 8192 + ldsoff);
            }
        }
        SB0();

        const int cb = kt % 3;
        const char* Ab = lds + cb * 8192;
        const char* Bb = lds + 24576 + cb * 8192;
        f16x8 af[4], bf[4];
        #pragma unroll
        for (int m = 0; m < 4; ++m)
            af[m] = *(const f16x8*)(Ab + (wm + m * 16 + lq) * 64 + lg * 16);
        #pragma unroll
        for (int n = 0; n < 4; ++n)
            bf[n] = *(const f16x8*)(Bb + (wn + n * 16 + lq) * 64 + lg * 16);
        __builtin_amdgcn_s_setprio(1);
        #pragma unroll
        for (int m = 0; m < 4; ++m)
            #pragma unroll
            for (int n = 0; n < 4; ++n)
                acc[m][n] = __builtin_amdgcn_mfma_f32_16x16x32_f16(af[m], bf[n], acc[m][n], 0, 0, 0);
        __builtin_amdgcn_s_setprio(0);
    }

    const float oscale = (z == 0) ? scq : 1.0f;
    #pragma unroll
    for (int m = 0; m < 4; ++m)
        #pragma unroll
        for (int n = 0; n < 4; ++n)
            #pragma unroll
            for (int r = 0; r < 4; ++r) {
                const int row = m0 + wm + m * 16 + lg * 4 + r;
                const int col = n0 + wn + n * 16 + lq;
                const float val = acc[m][n][r] * oscale;
                if (z < 2) {
                    C[(size_t)row * DD + col] = (f16)val;
                } else {
                    const int b = row >> 11, l = row & 2047;
                    const int h = col >> 6, dh = col & 63;
                    C[((size_t)((b * HH + h) * DHH + dh) << 11) + l] = (f16)val;
                }
            }
}

// ---------------- fallback f16-input GEMM (unchanged) ----------------
__global__ __launch_bounds__(256) void gemm_one(const f16* __restrict__ A, const f16* __restrict__ W,
                                                f16* __restrict__ C, int z) {
    __shared__ __align__(16) char lds[49152];
    const int tid = threadIdx.x, wid = tid >> 6, lane = tid & 63;
    const int m0 = blockIdx.y * 128, n0 = blockIdx.x * 128;
    const int lq = lane & 15, lg = lane >> 4;
    const int wm = (wid >> 1) << 6, wn = (wid & 1) << 6;
    f32x4 acc[4][4] = {};

    #pragma unroll
    for (int t = 0; t < 2; ++t)
        #pragma unroll
        for (int jj = 0; jj < 2; ++jj) {
            const int ldsoff = (wid * 2 + jj) << 10;
            const int o = ldsoff + lane * 16;
            const int row = o >> 6, c8 = (o >> 4) & 3;
            gload_lds16(A + (size_t)(m0 + row) * DD + t * 32 + c8 * 8, lds + t * 8192 + ldsoff);
            gload_lds16(W + (size_t)(n0 + row) * DD + t * 32 + c8 * 8, lds + 24576 + t * 8192 + ldsoff);
        }

    for (int kt = 0; kt < 32; ++kt) {
        VWAIT(4);
        SB0();
        __builtin_amdgcn_s_barrier();
        SB0();
        {
            const int nk = (kt + 2 < 32) ? kt + 2 : 31;
            const int nb = (kt + 2) % 3;
            #pragma unroll
            for (int jj = 0; jj < 2; ++jj) {
                const int ldsoff = (wid * 2 + jj) << 10;
                const int o = ldsoff + lane * 16;
                const int row = o >> 6, c8 = (o >> 4) & 3;
                gload_lds16(A + (size_t)(m0 + row) * DD + nk * 32 + c8 * 8,
                            lds + nb * 8192 + ldsoff);
                gload_lds16(W + (size_t)(n0 + row) * DD + nk * 32 + c8 * 8,
                            lds + 24576 + nb * 8192 + ldsoff);
            }
        }
        SB0();

        const int cb = kt % 3;
        const char* Ab = lds + cb * 8192;
        const char* Bb = lds + 24576 + cb * 8192;
        f16x8 af[4], bf[4];
        #pragma unroll
        for (int m = 0; m < 4; ++m)
            af[m] = *(const f16x8*)(Ab + (wm + m * 16 + lq) * 64 + lg * 16);
        #pragma unroll
        for (int n = 0; n < 4; ++n)
            bf[n] = *(const f16x8*)(Bb + (wn + n * 16 + lq) * 64 + lg * 16);
        __builtin_amdgcn_s_setprio(1);
        #pragma unroll
        for (int m = 0; m < 4; ++m)
            #pragma unroll
            for (int n = 0; n < 4; ++n)
                acc[m][n] = __builtin_amdgcn_mfma_f32_16x16x32_f16(af[m], bf[n], acc[m][n], 0, 0, 0);
        __builtin_amdgcn_s_setprio(0);
    }

    #pragma unroll
    for (int m = 0; m < 4; ++m)
        #pragma unroll
        for (int n = 0; n < 4; ++n)
            #pragma unroll
            for (int r = 0; r < 4; ++r) {
                const int row = m0 + wm + m * 16 + lg * 4 + r;
                const int col = n0 + wn + n * 16 + lq;
                const float val = acc[m][n][r];
                if (z < 2) {
                    C[(size_t)row * DD + col] = (f16)val;
                } else {
                    const int b = row >> 11, l = row & 2047;
                    const int h = col >> 6, dh = col & 63;
                    C[((size_t)((b * HH + h) * DHH + dh) << 11) + l] = (f16)val;
                }
            }
}

// ---------------- finale: gemm_out (blocks 0..511) + top_attn normalize (512..1535) ----------------
template<bool TOPF16>
__global__ __launch_bounds__(256) void finale(const f16* __restrict__ A, const f16* __restrict__ W,
                                              float* __restrict__ C, float* __restrict__ top,
                                              const void* __restrict__ src,
                                              const float* __restrict__ linvp) {
    __shared__ __align__(16) char lds[36864];
    const int tid = threadIdx.x;
    if (blockIdx.x >= 512) {
        int i = (blockIdx.x - 512) * 256 + tid;
        const int stride = 1024 * 256;
        if (TOPF16) {
            const f16x8* s8 = (const f16x8*)src;
            const int n = (int)((size_t)BB * LL * LL / 8);
            for (; i < n; i += stride) {
                f16x8 v = s8[i];
                const float linv = linvp[(i * 8) >> 11];
                float4 a, bq;
                a.x = (float)v[0] * linv; a.y = (float)v[1] * linv;
                a.z = (float)v[2] * linv; a.w = (float)v[3] * linv;
                bq.x = (float)v[4] * linv; bq.y = (float)v[5] * linv;
                bq.z = (float)v[6] * linv; bq.w = (float)v[7] * linv;
                ((float4*)top)[i * 2] = a;
                ((float4*)top)[i * 2 + 1] = bq;
            }
        } else {
            const int n = (int)((size_t)BB * LL * LL / 4);
            for (; i < n; i += stride) {
                float4 v = ((const float4*)top)[i];
                const float linv = linvp[(i * 4) >> 11];
                v.x = __builtin_amdgcn_exp2f(v.x) * linv;
                v.y = __builtin_amdgcn_exp2f(v.y) * linv;
                v.z = __builtin_amdgcn_exp2f(v.z) * linv;
                v.w = __builtin_amdgcn_exp2f(v.w) * linv;
                ((float4*)top)[i] = v;
            }
        }
        return;
    }
    const int bid = blockIdx.x;
    const int xcd = bid & 7, j = bid >> 3;
    const int yb = xcd * 4 + (j >> 4);
    const int xb = j & 15;
    const int wid = tid >> 6, lane = tid & 63;
    const int m0 = yb * 128, n0 = xb * 64;
    const int lq = lane & 15, lg = lane >> 4;
    const int wm = wid * 32;
    f32x4 acc[2][4] = {};

    #pragma unroll
    for (int t = 0; t < 2; ++t) {
        #pragma unroll
        for (int j2 = 0; j2 < 2; ++j2) {
            const int o = (j2 * 256 + tid) * 16;
            const int row = o >> 6, c8 = (o >> 4) & 3;
            gload_lds16(A + (size_t)(m0 + row) * DD + t * 32 + c8 * 8,
                        lds + t * 8192 + j2 * 4096 + (wid << 10));
        }
        {
            const int o = tid * 16;
            const int row = o >> 6, c8 = (o >> 4) & 3;
            gload_lds16(W + (size_t)(n0 + row) * DD + t * 32 + c8 * 8,
                        lds + 24576 + t * 4096 + (wid << 10));
        }
    }

    for (int kt = 0; kt < 32; ++kt) {
        VWAIT(3);
        SB0();
        __builtin_amdgcn_s_barrier();
        SB0();
        {
            const int nk = (kt + 2 < 32) ? kt + 2 : 31;
            const int nb = (kt + 2) % 3;
            #pragma unroll
            for (int j2 = 0; j2 < 2; ++j2) {
                const int o = (j2 * 256 + tid) * 16;
                const int row = o >> 6, c8 = (o >> 4) & 3;
                gload_lds16(A + (size_t)(m0 + row) * DD + nk * 32 + c8 * 8,
                            lds + nb * 8192 + j2 * 4096 + (wid << 10));
            }
            {
                const int o = tid * 16;
                const int row = o >> 6, c8 = (o >> 4) & 3;
                gload_lds16(W + (size_t)(n0 + row) * DD + nk * 32 + c8 * 8,
                            lds + 24576 + nb * 4096 + (wid << 10));
            }
        }
        SB0();

        const int cb = kt % 3;
        const char* Ab = lds + cb * 8192;
        const char* Bb = lds + 24576 + cb * 4096;
        f16x8 af[2], bf[4];
        #pragma unroll
        for (int m = 0; m < 2; ++m)
            af[m] = *(const f16x8*)(Ab + (wm + m * 16 + lq) * 64 + lg * 16);
        #pragma unroll
        for (int n = 0; n < 4; ++n)
            bf[n] = *(const f16x8*)(Bb + (n * 16 + lq) * 64 + lg * 16);
        __builtin_amdgcn_s_setprio(1);
        #pragma unroll
        for (int m = 0; m < 2; ++m)
            #pragma unroll
            for (int n = 0; n < 4; ++n)
                acc[m][n] = __builtin_amdgcn_mfma_f32_16x16x32_f16(af[m], bf[n], acc[m][n], 0, 0, 0);
        __builtin_amdgcn_s_setprio(0);
    }

    #pragma unroll
    for (int m = 0; m < 2; ++m)
        #pragma unroll
        for (int n = 0; n < 4; ++n)
            #pragma unroll
            for (int r = 0; r < 4; ++r) {
                const int row = m0 + wm + m * 16 + lg * 4 + r;
                const int col = n0 + n * 16 + lq;
                C[(size_t)row * DD + col] = acc[m][n][r];
            }
}

// ---------------- Flash attention (R7/R9-proven 4-wave version, unchanged) ----------------
template<bool TOPF16>
__global__ __launch_bounds__(256) void attn_fwd(const f16* __restrict__ Qp, const f16* __restrict__ Kp,
                                                const f16* __restrict__ VTp,
                                                const u64* __restrict__ Mp,
                                                f16* __restrict__ Op, void* __restrict__ topout,
                                                float* __restrict__ statsLinv) {
    extern __shared__ char lds[];
    const int tid = threadIdx.x, wid = tid >> 6, lane = tid & 63;
    const int lq = lane & 15, lg = lane >> 4;
    const int bid = blockIdx.x;
    const int xcd = bid & 7, j = bid >> 3;
    const int bh = xcd * 4 + (j >> 5);
    const int qt = j & 31;
    const int b = bh >> 4, h = bh & 15;
    const bool topblk = (h == 0);
    const int qrow = qt * 64 + wid * 16 + lq;

    f16x8 qf[2];
    #pragma unroll
    for (int kk = 0; kk < 2; ++kk)
        qf[kk] = *(const f16x8*)(Qp + (size_t)(b * LL + qrow) * DD + h * 64 + (kk * 4 + lg) * 8);

    {
        #pragma unroll
        for (int jj = 0; jj < 2; ++jj) {
            const int o = (wid * 2 + jj) * 1024 + lane * 16;
            const int row = o >> 7, sc = ((o >> 4) & 7) ^ (row & 7);
            gload_lds16(Kp + (size_t)(b * LL + row) * DD + h * 64 + sc * 8,
                        lds + 8192 + (wid * 2 + jj) * 1024);
            gload_lds16(VTp + (size_t)((b * HH + h) * DHH + row) * LL + sc * 8,
                        lds + 24576 + (wid * 2 + jj) * 1024);
        }
    }

    float lsum = 0.f;
    f32x4 acc[4] = {};

    for (int kt = 0; kt < 32; ++kt) {
        if (topblk && kt > 0) { VWAIT(4); } else { VWAIT(0); }
        SB0();
        __builtin_amdgcn_s_barrier();
        SB0();
        const u64 cm = Mp[((size_t)b * 32 + kt) * LL + qrow];
        SB0();
        {
            const int nk = (kt + 1 < 32) ? kt + 1 : 31;
            const int nb = (kt + 1) & 1;
            #pragma unroll
            for (int jj = 0; jj < 2; ++jj) {
                const int o = (wid * 2 + jj) * 1024 + lane * 16;
                const int row = o >> 7, sc = ((o >> 4) & 7) ^ (row & 7);
                gload_lds16(Kp + (size_t)(b * LL + nk * 64 + row) * DD + h * 64 + sc * 8,
                            lds + 8192 + nb * 8192 + (wid * 2 + jj) * 1024);
                gload_lds16(VTp + (size_t)((b * HH + h) * DHH + row) * LL + nk * 64 + sc * 8,
                            lds + 24576 + nb * 8192 + (wid * 2 + jj) * 1024);
            }
        }
        SB0();

        const int cb = kt & 1;
        const char* Kb = lds + 8192 + cb * 8192;
        const char* Vb = lds + 24576 + cb * 8192;

        f32x4 s[4] = {};
        __builtin_amdgcn_s_setprio(1);
        #pragma unroll
        for (int f = 0; f < 4; ++f)
            #pragma unroll
            for (int kk = 0; kk < 2; ++kk) {
                const int co = (((kk * 4 + lg) ^ (lq & 7)) << 4);
                f16x8 kf = *(const f16x8*)(Kb + (f * 16 + lq) * 128 + co);
                s[f] = __builtin_amdgcn_mfma_f32_16x16x32_f16(kf, qf[kk], s[f], 0, 0, 0);
            }
        __builtin_amdgcn_s_setprio(0);

        const u64 wsh = cm >> (lg * 4);
        const unsigned lo = (unsigned)wsh, hi = (unsigned)(wsh >> 32);
        f16x4 ph[4];
        #pragma unroll
        for (int f = 0; f < 4; ++f) {
            const unsigned nib = ((f < 2) ? (lo >> (f * 16)) : (hi >> ((f - 2) * 16))) & 0xFu;
            #pragma unroll
            for (int r = 0; r < 4; ++r)
                if (nib & (1u << r)) s[f][r] = -1e18f;
            const float p0 = __builtin_amdgcn_exp2f(s[f][0]);
            const float p1 = __builtin_amdgcn_exp2f(s[f][1]);
            const float p2 = __builtin_amdgcn_exp2f(s[f][2]);
            const float p3 = __builtin_amdgcn_exp2f(s[f][3]);
            lsum += (p0 + p1) + (p2 + p3);
            f16x2 pa = __builtin_bit_cast(f16x2, __builtin_amdgcn_cvt_pkrtz(p0, p1));
            f16x2 pb = __builtin_bit_cast(f16x2, __builtin_amdgcn_cvt_pkrtz(p2, p3));
            ph[f][0] = pa[0]; ph[f][1] = pa[1]; ph[f][2] = pb[0]; ph[f][3] = pb[1];
        }

        if (topblk) {
            if (TOPF16) {
                f16* T = (f16*)topout;
                #pragma unroll
                for (int f = 0; f < 4; ++f)
                    *(f16x4*)(T + ((size_t)b * LL + qrow) * LL + kt * 64 + f * 16 + lg * 4) = ph[f];
            } else {
                float* T = (float*)topout;
                #pragma unroll
                for (int f = 0; f < 4; ++f)
                    *(f32x4*)(T + ((size_t)b * LL + qrow) * LL + kt * 64 + f * 16 + lg * 4) = s[f];
            }
        }

        #pragma unroll
        for (int f = 0; f < 4; ++f) {
            const int chunk = f * 2 + (lg >> 1);
            const int bo = ((chunk ^ (lq & 7)) << 4) + (lg & 1) * 8;
            *(f16x4*)(lds + (wid << 11) + lq * 128 + bo) = ph[f];
        }

        __builtin_amdgcn_s_setprio(1);
        #pragma unroll
        for (int kk = 0; kk < 2; ++kk) {
            const int co = (((kk * 4 + lg) ^ (lq & 7)) << 4);
            f16x8 pf = *(const f16x8*)(lds + (wid << 11) + lq * 128 + co);
            #pragma unroll
            for (int f = 0; f < 4; ++f) {
                f16x8 vf = *(const f16x8*)(Vb + (f * 16 + lq) * 128 + co);
                acc[f] = __builtin_amdgcn_mfma_f32_16x16x32_f16(vf, pf, acc[f], 0, 0, 0);
            }
        }
        __builtin_amdgcn_s_setprio(0);
    }

    lsum += __shfl_xor(lsum, 16);
    lsum += __shfl_xor(lsum, 32);
    const float linv = 1.f / lsum;
    #pragma unroll
    for (int f = 0; f < 4; ++f) {
        f16x4 ov;
        #pragma unroll
        for (int r = 0; r < 4; ++r) ov[r] = (f16)(acc[f][r] * linv);
        *(f16x4*)(Op + (size_t)(b * LL + qrow) * DD + h * 64 + f * 16 + lg * 4) = ov;
    }
    if (topblk && lg == 0) statsLinv[(size_t)b * LL + qrow] = linv;
}

// ---------------- launch ----------------
extern "C" void kernel_launch(void* const* d_in, const int* in_sizes, int n_in,
                              void* d_out, int out_size, void* d_ws, size_t ws_size,
                              hipStream_t stream) {
    const float* q   = (const float*)d_in[0];
    const float* k   = (const float*)d_in[1];
    const float* v   = (const float*)d_in[2];
    const int*   msk = (const int*)d_in[3];
    const float* wq  = (const float*)d_in[4];
    const float* wk  = (const float*)d_in[5];
    const float* wv  = (const float*)d_in[6];
    const float* wo  = (const float*)d_in[7];
    float* out = (float*)d_out;

    const size_t NX = (size_t)BB * LL * DD;
    const size_t NW = (size_t)DD * DD;
    const int NMW = BB * LL * (LL / 64);
    const size_t NXo = NX;
    const float SCQ = 0.125f * 1.4426950408889634f;
    const int ALDS = 40960;

    f16* ws = (f16*)d_ws;
    const size_t needed = (6 * NX + 4 * NW) * 2 + (size_t)NMW * 8 + (size_t)BB * LL * 4;
    const bool fused = ws_size >= needed;

    if (fused) {
        f16* Op   = ws;
        f16* wh   = Op + NX;
        f16* wqh = wh, *wkh = wh + NW, *wvh = wh + 2 * NW, *woh = wh + 3 * NW;
        f16* Qp  = wh + 4 * NW;
        f16* Kp  = Qp + NX;
        f16* VTp = Kp + NX;
        f16* topP = VTp + NX;
        u64* Mp  = (u64*)(topP + 2 * NX);
        float* statsLinv = (float*)(Mp + NMW);

        prep_w<<<1024, 256, 0, stream>>>(wq, wk, wv, wo, wh);
        gemm_qkv<<<896, 256, 0, stream>>>(q, k, v, wqh, wkh, wvh, Qp, Kp, VTp, SCQ, msk, Mp);
        attn_fwd<true><<<1024, 256, ALDS, stream>>>(Qp, Kp, VTp, Mp, Op, topP, statsLinv);
        finale<true><<<1536, 256, 0, stream>>>(Op, woh, out, out + NXo, topP, statsLinv);
    } else {
        f16* bufA = ws;
        f16* wh   = bufA + NX;
        f16* wqh = wh, *wkh = wh + NW, *wvh = wh + 2 * NW, *woh = wh + 3 * NW;
        f16* Qp  = wh + 4 * NW;
        f16* Kp  = Qp + NX;
        f16* VTp = Kp + NX;
        u64* Mp  = (u64*)(VTp + NX);
        float* statsLinv = (float*)(Mp + NMW);

        pack_mask<<<256, 256, 0, stream>>>(msk, Mp, NMW);
        cvt4_kernel<<<dim3(128, 4), 256, 0, stream>>>(wq, wk, wv, wo, wh, (int)(NW / 4));
        cvt_kernel<<<2048, 256, 0, stream>>>(q, bufA, (int)(NX / 4), SCQ);
        gemm_one<<<dim3(8, 32), 256, 0, stream>>>(bufA, wqh, Qp, 0);
        cvt_kernel<<<2048, 256, 0, stream>>>(k, bufA, (int)(NX / 4), 1.f);
        gemm_one<<<dim3(8, 32), 256, 0, stream>>>(bufA, wkh, Kp, 1);
        cvt_kernel<<<2048, 256, 0, stream>>>(v, bufA, (int)(NX / 4), 1.f);
        gemm_one<<<dim3(8, 32), 256, 0, stream>>>(bufA, wvh, VTp, 2);
        attn_fwd<false><<<1024, 256, ALDS, stream>>>(Qp, Kp, VTp, Mp, bufA,
                                                     out + NXo, statsLinv);
        finale<false><<<1536, 256, 0, stream>>>(bufA, woh, out, out + NXo, out + NXo, statsLinv);
    }
}

// Round 18
// 155.568 us; speedup vs baseline: 1.0388x; 1.0388x over previous
//
#include <hip/hip_runtime.h>

#define BB 2
#define LL 2048
#define DD 1024
#define HH 16
#define DHH 64

typedef _Float16 f16;
typedef _Float16 f16x8 __attribute__((ext_vector_type(8)));
typedef _Float16 f16x4 __attribute__((ext_vector_type(4)));
typedef _Float16 f16x2 __attribute__((ext_vector_type(2)));
typedef float f32x4 __attribute__((ext_vector_type(4)));
typedef unsigned long long u64;

#define VWAIT(N) asm volatile("s_waitcnt vmcnt(" #N ")" ::: "memory")
#define LWAIT0() asm volatile("s_waitcnt lgkmcnt(0)" ::: "memory")
#define SB0() __builtin_amdgcn_sched_barrier(0)

__device__ __forceinline__ void gload_lds16(const void* g, void* l) {
    __builtin_amdgcn_global_load_lds(
        (const __attribute__((address_space(1))) void*)g,
        (__attribute__((address_space(3))) void*)l, 16, 0, 0);
}

__device__ __forceinline__ f16x4 cvt4f(float4 v) {
    f16x4 o;
    o[0] = (f16)v.x; o[1] = (f16)v.y; o[2] = (f16)v.z; o[3] = (f16)v.w;
    return o;
}

__device__ __forceinline__ f16x8 cvt8f(float4 a, float4 b) {
    f16x2 p0 = __builtin_bit_cast(f16x2, __builtin_amdgcn_cvt_pkrtz(a.x, a.y));
    f16x2 p1 = __builtin_bit_cast(f16x2, __builtin_amdgcn_cvt_pkrtz(a.z, a.w));
    f16x2 p2 = __builtin_bit_cast(f16x2, __builtin_amdgcn_cvt_pkrtz(b.x, b.y));
    f16x2 p3 = __builtin_bit_cast(f16x2, __builtin_amdgcn_cvt_pkrtz(b.z, b.w));
    f16x8 r;
    r[0] = p0[0]; r[1] = p0[1]; r[2] = p1[0]; r[3] = p1[1];
    r[4] = p2[0]; r[5] = p2[1]; r[6] = p3[0]; r[7] = p3[1];
    return r;
}

// ---------------- prep: mask pack + weight conversion (q/k/v conversion fused into GEMM) ----------------
__global__ void prep(const int* __restrict__ msk,
                     const float* __restrict__ wq, const float* __restrict__ wk,
                     const float* __restrict__ wv, const float* __restrict__ wo,
                     f16* __restrict__ wh, u64* __restrict__ Mp) {
    const int tid = threadIdx.x;
    if (blockIdx.y == 0) {
        const int lane = tid & 63;
        int w = (blockIdx.x * 256 + tid) >> 6;
        const int nw = (1024 * 256) >> 6;
        for (; w < BB * LL * 32; w += nw) {
            int mv = msk[(size_t)w * 64 + lane];
            u64 bits = __ballot(mv != 0);
            if (lane == 0) {
                const int kt = w & 31;
                const int bq = w >> 5;
                const int qq = bq & 2047, b = bq >> 11;
                Mp[((size_t)b * 32 + kt) * LL + qq] = bits;
            }
        }
    } else {
        int i = blockIdx.x * 256 + tid;
        const int stride = 1024 * 256;
        for (; i < 4 * 262144; i += stride) {
            const int sel = i >> 18, j = i & 262143;
            const float* s = sel == 0 ? wq : sel == 1 ? wk : sel == 2 ? wv : wo;
            ((f16x4*)wh)[i] = cvt4f(((const float4*)s)[j]);
        }
    }
}

// standalone pieces for the fallback path
__global__ void cvt_kernel(const float* __restrict__ src, f16* __restrict__ dst, int n4, float sc) {
    int i = blockIdx.x * blockDim.x + threadIdx.x;
    const int stride = gridDim.x * blockDim.x;
    for (; i < n4; i += stride) {
        float4 v = ((const float4*)src)[i];
        v.x *= sc; v.y *= sc; v.z *= sc; v.w *= sc;
        ((f16x4*)dst)[i] = cvt4f(v);
    }
}
__global__ void cvt4_kernel(const float* __restrict__ a, const float* __restrict__ b,
                            const float* __restrict__ c, const float* __restrict__ d,
                            f16* __restrict__ dst, int n4) {
    const float* s = blockIdx.y == 0 ? a : blockIdx.y == 1 ? b : blockIdx.y == 2 ? c : d;
    f16* o = dst + (size_t)blockIdx.y * n4 * 4;
    int i = blockIdx.x * blockDim.x + threadIdx.x;
    const int stride = gridDim.x * blockDim.x;
    for (; i < n4; i += stride)
        ((f16x4*)o)[i] = cvt4f(((const float4*)s)[i]);
}
__global__ void pack_mask(const int* __restrict__ mask, u64* __restrict__ out, int nwords) {
    const int lane = threadIdx.x & 63;
    int w = (blockIdx.x * blockDim.x + threadIdx.x) >> 6;
    const int nw = (gridDim.x * blockDim.x) >> 6;
    for (; w < nwords; w += nw) {
        int mv = mask[(size_t)w * 64 + lane];
        u64 bits = __ballot(mv != 0);
        if (lane == 0) {
            const int kt = w & 31;
            const int bq = w >> 5;
            const int qq = bq & 2047, b = bq >> 11;
            out[((size_t)b * 32 + kt) * LL + qq] = bits;
        }
    }
}

// ---------------- fused QKV projection GEMM with inline f32->f16 A conversion (R9) ----------------
// A f32 staged via reg (load dwordx4 x2 -> cvt_pkrtz -> ds_write_b128), W f16 via
// global_load_lds. 3-buffer LDS, depth-2 W lead, VWAIT(2). 768 blocks, XCD-swizzled.
__global__ __launch_bounds__(256) void gemm_qkv(
        const float* __restrict__ A0, const float* __restrict__ A1, const float* __restrict__ A2,
        const f16* __restrict__ W0, const f16* __restrict__ W1, const f16* __restrict__ W2,
        f16* __restrict__ C0, f16* __restrict__ C1, f16* __restrict__ C2, float scq) {
    __shared__ __align__(16) char lds[49152];
    const int bid = blockIdx.x;
    const int xcd = bid & 7, j = bid >> 3;      // j 0..95
    const int p = xcd * 12 + (j >> 3);          // A-panel index 0..95
    const int xb = j & 7;
    const int z = p >> 5, yb = p & 31;
    const float* __restrict__ A = z == 0 ? A0 : z == 1 ? A1 : A2;
    const f16* __restrict__ W = z == 0 ? W0 : z == 1 ? W1 : W2;
    f16* __restrict__ C       = z == 0 ? C0 : z == 1 ? C1 : C2;

    const int tid = threadIdx.x, wid = tid >> 6, lane = tid & 63;
    const int m0 = yb * 128, n0 = xb * 128;
    const int lq = lane & 15, lg = lane >> 4;
    const int wm = (wid >> 1) << 6, wn = (wid & 1) << 6;
    const int ar0 = (wid * 2) * 16 + (lane >> 2);
    const int ar1 = (wid * 2 + 1) * 16 + (lane >> 2);
    const int ac8 = lane & 3;
    const float* a0p = A + (size_t)(m0 + ar0) * DD + ac8 * 8;
    const float* a1p = A + (size_t)(m0 + ar1) * DD + ac8 * 8;
    char* aw0 = lds + ar0 * 64 + ac8 * 16;      // + buf*8192
    char* aw1 = lds + ar1 * 64 + ac8 * 16;

    f32x4 acc[4][4] = {};
    float4 arA[2][2], arB[2][2];                // two reg sets, [slot][half]

    // ---- prologue: write A(0),A(1) to LDS; load A(2)->arA; issue W(0),W(1) ----
    {
        float4 t00 = *(const float4*)(a0p + 0 * 32);
        float4 t01 = *(const float4*)(a0p + 0 * 32 + 4);
        float4 t10 = *(const float4*)(a1p + 0 * 32);
        float4 t11 = *(const float4*)(a1p + 0 * 32 + 4);
        VWAIT(0);
        *(f16x8*)(aw0 + 0 * 8192) = cvt8f(t00, t01);
        *(f16x8*)(aw1 + 0 * 8192) = cvt8f(t10, t11);
        t00 = *(const float4*)(a0p + 1 * 32);
        t01 = *(const float4*)(a0p + 1 * 32 + 4);
        t10 = *(const float4*)(a1p + 1 * 32);
        t11 = *(const float4*)(a1p + 1 * 32 + 4);
        VWAIT(0);
        *(f16x8*)(aw0 + 1 * 8192) = cvt8f(t00, t01);
        *(f16x8*)(aw1 + 1 * 8192) = cvt8f(t10, t11);
        SB0();
        arA[0][0] = *(const float4*)(a0p + 2 * 32);
        arA[0][1] = *(const float4*)(a0p + 2 * 32 + 4);
        arA[1][0] = *(const float4*)(a1p + 2 * 32);
        arA[1][1] = *(const float4*)(a1p + 2 * 32 + 4);
        SB0();
        #pragma unroll
        for (int t = 0; t < 2; ++t)
            #pragma unroll
            for (int jj = 0; jj < 2; ++jj) {
                const int ldsoff = (wid * 2 + jj) << 10;
                const int o = ldsoff + lane * 16;
                const int row = o >> 6, c8 = (o >> 4) & 3;
                gload_lds16(W + (size_t)(n0 + row) * DD + t * 32 + c8 * 8,
                            lds + 24576 + t * 8192 + ldsoff);
            }
        LWAIT0();   // prologue ds_writes visible before first barrier
    }

    #pragma unroll
    for (int kt = 0; kt < 32; ++kt) {
        VWAIT(2);   // A(kt+2) regs + W(kt) done; W(kt+1) stays in flight
        SB0();
        __builtin_amdgcn_s_barrier();
        SB0();
        // ds_write A(kt+2) from reg set (kt&1); load A(kt+3) into the other set
        {
            const int wb = (kt + 2) % 3;
            const int nk = (kt + 3 < 32) ? kt + 3 : 31;
            if ((kt & 1) == 0) {
                *(f16x8*)(aw0 + wb * 8192) = cvt8f(arA[0][0], arA[0][1]);
                *(f16x8*)(aw1 + wb * 8192) = cvt8f(arA[1][0], arA[1][1]);
                SB0();
                arB[0][0] = *(const float4*)(a0p + nk * 32);
                arB[0][1] = *(const float4*)(a0p + nk * 32 + 4);
                arB[1][0] = *(const float4*)(a1p + nk * 32);
                arB[1][1] = *(const float4*)(a1p + nk * 32 + 4);
            } else {
                *(f16x8*)(aw0 + wb * 8192) = cvt8f(arB[0][0], arB[0][1]);
                *(f16x8*)(aw1 + wb * 8192) = cvt8f(arB[1][0], arB[1][1]);
                SB0();
                arA[0][0] = *(const float4*)(a0p + nk * 32);
                arA[0][1] = *(const float4*)(a0p + nk * 32 + 4);
                arA[1][0] = *(const float4*)(a1p + nk * 32);
                arA[1][1] = *(const float4*)(a1p + nk * 32 + 4);
            }
        }
        SB0();
        // issue W(kt+2) staged loads
        {
            const int nk = (kt + 2 < 32) ? kt + 2 : 31;
            const int nb = (kt + 2) % 3;
            #pragma unroll
            for (int jj = 0; jj < 2; ++jj) {
                const int ldsoff = (wid * 2 + jj) << 10;
                const int o = ldsoff + lane * 16;
                const int row = o >> 6, c8 = (o >> 4) & 3;
                gload_lds16(W + (size_t)(n0 + row) * DD + nk * 32 + c8 * 8,
                            lds + 24576 + nb * 8192 + ldsoff);
            }
        }
        SB0();

        const int cb = kt % 3;
        const char* Ab = lds + cb * 8192;
        const char* Bb = lds + 24576 + cb * 8192;
        f16x8 af[4], bf[4];
        #pragma unroll
        for (int m = 0; m < 4; ++m)
            af[m] = *(const f16x8*)(Ab + (wm + m * 16 + lq) * 64 + lg * 16);
        #pragma unroll
        for (int n = 0; n < 4; ++n)
            bf[n] = *(const f16x8*)(Bb + (wn + n * 16 + lq) * 64 + lg * 16);
        __builtin_amdgcn_s_setprio(1);
        #pragma unroll
        for (int m = 0; m < 4; ++m)
            #pragma unroll
            for (int n = 0; n < 4; ++n)
                acc[m][n] = __builtin_amdgcn_mfma_f32_16x16x32_f16(af[m], bf[n], acc[m][n], 0, 0, 0);
        __builtin_amdgcn_s_setprio(0);
    }

    const float oscale = (z == 0) ? scq : 1.0f;
    #pragma unroll
    for (int m = 0; m < 4; ++m)
        #pragma unroll
        for (int n = 0; n < 4; ++n)
            #pragma unroll
            for (int r = 0; r < 4; ++r) {
                const int row = m0 + wm + m * 16 + lg * 4 + r;
                const int col = n0 + wn + n * 16 + lq;
                const float val = acc[m][n][r] * oscale;
                if (z < 2) {
                    C[(size_t)row * DD + col] = (f16)val;
                } else {
                    const int b = row >> 11, l = row & 2047;
                    const int h = col >> 6, dh = col & 63;
                    C[((size_t)((b * HH + h) * DHH + dh) << 11) + l] = (f16)val;
                }
            }
}

// ---------------- fallback f16-input GEMM ----------------
__global__ __launch_bounds__(256) void gemm_one(const f16* __restrict__ A, const f16* __restrict__ W,
                                                f16* __restrict__ C, int z) {
    __shared__ __align__(16) char lds[49152];
    const int tid = threadIdx.x, wid = tid >> 6, lane = tid & 63;
    const int m0 = blockIdx.y * 128, n0 = blockIdx.x * 128;
    const int lq = lane & 15, lg = lane >> 4;
    const int wm = (wid >> 1) << 6, wn = (wid & 1) << 6;
    f32x4 acc[4][4] = {};

    #pragma unroll
    for (int t = 0; t < 2; ++t)
        #pragma unroll
        for (int jj = 0; jj < 2; ++jj) {
            const int ldsoff = (wid * 2 + jj) << 10;
            const int o = ldsoff + lane * 16;
            const int row = o >> 6, c8 = (o >> 4) & 3;
            gload_lds16(A + (size_t)(m0 + row) * DD + t * 32 + c8 * 8, lds + t * 8192 + ldsoff);
            gload_lds16(W + (size_t)(n0 + row) * DD + t * 32 + c8 * 8, lds + 24576 + t * 8192 + ldsoff);
        }

    for (int kt = 0; kt < 32; ++kt) {
        VWAIT(4);
        SB0();
        __builtin_amdgcn_s_barrier();
        SB0();
        {
            const int nk = (kt + 2 < 32) ? kt + 2 : 31;
            const int nb = (kt + 2) % 3;
            #pragma unroll
            for (int jj = 0; jj < 2; ++jj) {
                const int ldsoff = (wid * 2 + jj) << 10;
                const int o = ldsoff + lane * 16;
                const int row = o >> 6, c8 = (o >> 4) & 3;
                gload_lds16(A + (size_t)(m0 + row) * DD + nk * 32 + c8 * 8,
                            lds + nb * 8192 + ldsoff);
                gload_lds16(W + (size_t)(n0 + row) * DD + nk * 32 + c8 * 8,
                            lds + 24576 + nb * 8192 + ldsoff);
            }
        }
        SB0();

        const int cb = kt % 3;
        const char* Ab = lds + cb * 8192;
        const char* Bb = lds + 24576 + cb * 8192;
        f16x8 af[4], bf[4];
        #pragma unroll
        for (int m = 0; m < 4; ++m)
            af[m] = *(const f16x8*)(Ab + (wm + m * 16 + lq) * 64 + lg * 16);
        #pragma unroll
        for (int n = 0; n < 4; ++n)
            bf[n] = *(const f16x8*)(Bb + (wn + n * 16 + lq) * 64 + lg * 16);
        __builtin_amdgcn_s_setprio(1);
        #pragma unroll
        for (int m = 0; m < 4; ++m)
            #pragma unroll
            for (int n = 0; n < 4; ++n)
                acc[m][n] = __builtin_amdgcn_mfma_f32_16x16x32_f16(af[m], bf[n], acc[m][n], 0, 0, 0);
        __builtin_amdgcn_s_setprio(0);
    }

    #pragma unroll
    for (int m = 0; m < 4; ++m)
        #pragma unroll
        for (int n = 0; n < 4; ++n)
            #pragma unroll
            for (int r = 0; r < 4; ++r) {
                const int row = m0 + wm + m * 16 + lg * 4 + r;
                const int col = n0 + wn + n * 16 + lq;
                const float val = acc[m][n][r];
                if (z < 2) {
                    C[(size_t)row * DD + col] = (f16)val;
                } else {
                    const int b = row >> 11, l = row & 2047;
                    const int h = col >> 6, dh = col & 63;
                    C[((size_t)((b * HH + h) * DHH + dh) << 11) + l] = (f16)val;
                }
            }
}

// ---------------- finale: gemm_out (blocks 0..511) + top_attn normalize (blocks 512..1535) ----------------
template<bool TOPF16>
__global__ __launch_bounds__(256) void finale(const f16* __restrict__ A, const f16* __restrict__ W,
                                              float* __restrict__ C, float* __restrict__ top,
                                              const void* __restrict__ src,
                                              const float* __restrict__ linvp) {
    __shared__ __align__(16) char lds[36864];
    const int tid = threadIdx.x;
    if (blockIdx.x >= 512) {
        int i = (blockIdx.x - 512) * 256 + tid;
        const int stride = 1024 * 256;
        if (TOPF16) {
            const f16x8* s8 = (const f16x8*)src;
            const int n = (int)((size_t)BB * LL * LL / 8);
            for (; i < n; i += stride) {
                f16x8 v = s8[i];
                const float linv = linvp[(i * 8) >> 11];
                float4 a, bq;
                a.x = (float)v[0] * linv; a.y = (float)v[1] * linv;
                a.z = (float)v[2] * linv; a.w = (float)v[3] * linv;
                bq.x = (float)v[4] * linv; bq.y = (float)v[5] * linv;
                bq.z = (float)v[6] * linv; bq.w = (float)v[7] * linv;
                ((float4*)top)[i * 2] = a;
                ((float4*)top)[i * 2 + 1] = bq;
            }
        } else {
            const int n = (int)((size_t)BB * LL * LL / 4);
            for (; i < n; i += stride) {
                float4 v = ((const float4*)top)[i];
                const float linv = linvp[(i * 4) >> 11];
                v.x = __builtin_amdgcn_exp2f(v.x) * linv;
                v.y = __builtin_amdgcn_exp2f(v.y) * linv;
                v.z = __builtin_amdgcn_exp2f(v.z) * linv;
                v.w = __builtin_amdgcn_exp2f(v.w) * linv;
                ((float4*)top)[i] = v;
            }
        }
        return;
    }
    const int bid = blockIdx.x;
    const int xcd = bid & 7, j = bid >> 3;
    const int yb = xcd * 4 + (j >> 4);
    const int xb = j & 15;
    const int wid = tid >> 6, lane = tid & 63;
    const int m0 = yb * 128, n0 = xb * 64;
    const int lq = lane & 15, lg = lane >> 4;
    const int wm = wid * 32;
    f32x4 acc[2][4] = {};

    #pragma unroll
    for (int t = 0; t < 2; ++t) {
        #pragma unroll
        for (int j2 = 0; j2 < 2; ++j2) {
            const int o = (j2 * 256 + tid) * 16;
            const int row = o >> 6, c8 = (o >> 4) & 3;
            gload_lds16(A + (size_t)(m0 + row) * DD + t * 32 + c8 * 8,
                        lds + t * 8192 + j2 * 4096 + (wid << 10));
        }
        {
            const int o = tid * 16;
            const int row = o >> 6, c8 = (o >> 4) & 3;
            gload_lds16(W + (size_t)(n0 + row) * DD + t * 32 + c8 * 8,
                        lds + 24576 + t * 4096 + (wid << 10));
        }
    }

    for (int kt = 0; kt < 32; ++kt) {
        VWAIT(3);
        SB0();
        __builtin_amdgcn_s_barrier();
        SB0();
        {
            const int nk = (kt + 2 < 32) ? kt + 2 : 31;
            const int nb = (kt + 2) % 3;
            #pragma unroll
            for (int j2 = 0; j2 < 2; ++j2) {
                const int o = (j2 * 256 + tid) * 16;
                const int row = o >> 6, c8 = (o >> 4) & 3;
                gload_lds16(A + (size_t)(m0 + row) * DD + nk * 32 + c8 * 8,
                            lds + nb * 8192 + j2 * 4096 + (wid << 10));
            }
            {
                const int o = tid * 16;
                const int row = o >> 6, c8 = (o >> 4) & 3;
                gload_lds16(W + (size_t)(n0 + row) * DD + nk * 32 + c8 * 8,
                            lds + 24576 + nb * 4096 + (wid << 10));
            }
        }
        SB0();

        const int cb = kt % 3;
        const char* Ab = lds + cb * 8192;
        const char* Bb = lds + 24576 + cb * 4096;
        f16x8 af[2], bf[4];
        #pragma unroll
        for (int m = 0; m < 2; ++m)
            af[m] = *(const f16x8*)(Ab + (wm + m * 16 + lq) * 64 + lg * 16);
        #pragma unroll
        for (int n = 0; n < 4; ++n)
            bf[n] = *(const f16x8*)(Bb + (n * 16 + lq) * 64 + lg * 16);
        __builtin_amdgcn_s_setprio(1);
        #pragma unroll
        for (int m = 0; m < 2; ++m)
            #pragma unroll
            for (int n = 0; n < 4; ++n)
                acc[m][n] = __builtin_amdgcn_mfma_f32_16x16x32_f16(af[m], bf[n], acc[m][n], 0, 0, 0);
        __builtin_amdgcn_s_setprio(0);
    }

    #pragma unroll
    for (int m = 0; m < 2; ++m)
        #pragma unroll
        for (int n = 0; n < 4; ++n)
            #pragma unroll
            for (int r = 0; r < 4; ++r) {
                const int row = m0 + wm + m * 16 + lg * 4 + r;
                const int col = n0 + n * 16 + lq;
                C[(size_t)row * DD + col] = acc[m][n][r];
            }
}

// ---------------- Flash attention (R7-proven 4-wave version, unchanged) ----------------
template<bool TOPF16>
__global__ __launch_bounds__(256) void attn_fwd(const f16* __restrict__ Qp, const f16* __restrict__ Kp,
                                                const f16* __restrict__ VTp,
                                                const u64* __restrict__ Mp,
                                                f16* __restrict__ Op, void* __restrict__ topout,
                                                float* __restrict__ statsLinv) {
    extern __shared__ char lds[];
    const int tid = threadIdx.x, wid = tid >> 6, lane = tid & 63;
    const int lq = lane & 15, lg = lane >> 4;
    const int bid = blockIdx.x;
    const int xcd = bid & 7, j = bid >> 3;
    const int bh = xcd * 4 + (j >> 5);
    const int qt = j & 31;
    const int b = bh >> 4, h = bh & 15;
    const bool topblk = (h == 0);
    const int qrow = qt * 64 + wid * 16 + lq;

    f16x8 qf[2];
    #pragma unroll
    for (int kk = 0; kk < 2; ++kk)
        qf[kk] = *(const f16x8*)(Qp + (size_t)(b * LL + qrow) * DD + h * 64 + (kk * 4 + lg) * 8);

    {
        #pragma unroll
        for (int jj = 0; jj < 2; ++jj) {
            const int o = (wid * 2 + jj) * 1024 + lane * 16;
            const int row = o >> 7, sc = ((o >> 4) & 7) ^ (row & 7);
            gload_lds16(Kp + (size_t)(b * LL + row) * DD + h * 64 + sc * 8,
                        lds + 8192 + (wid * 2 + jj) * 1024);
            gload_lds16(VTp + (size_t)((b * HH + h) * DHH + row) * LL + sc * 8,
                        lds + 24576 + (wid * 2 + jj) * 1024);
        }
    }

    float lsum = 0.f;
    f32x4 acc[4] = {};

    for (int kt = 0; kt < 32; ++kt) {
        if (topblk && kt > 0) { VWAIT(4); } else { VWAIT(0); }
        SB0();
        __builtin_amdgcn_s_barrier();
        SB0();
        const u64 cm = Mp[((size_t)b * 32 + kt) * LL + qrow];
        SB0();
        {
            const int nk = (kt + 1 < 32) ? kt + 1 : 31;
            const int nb = (kt + 1) & 1;
            #pragma unroll
            for (int jj = 0; jj < 2; ++jj) {
                const int o = (wid * 2 + jj) * 1024 + lane * 16;
                const int row = o >> 7, sc = ((o >> 4) & 7) ^ (row & 7);
                gload_lds16(Kp + (size_t)(b * LL + nk * 64 + row) * DD + h * 64 + sc * 8,
                            lds + 8192 + nb * 8192 + (wid * 2 + jj) * 1024);
                gload_lds16(VTp + (size_t)((b * HH + h) * DHH + row) * LL + nk * 64 + sc * 8,
                            lds + 24576 + nb * 8192 + (wid * 2 + jj) * 1024);
            }
        }
        SB0();

        const int cb = kt & 1;
        const char* Kb = lds + 8192 + cb * 8192;
        const char* Vb = lds + 24576 + cb * 8192;

        f32x4 s[4] = {};
        __builtin_amdgcn_s_setprio(1);
        #pragma unroll
        for (int f = 0; f < 4; ++f)
            #pragma unroll
            for (int kk = 0; kk < 2; ++kk) {
                const int co = (((kk * 4 + lg) ^ (lq & 7)) << 4);
                f16x8 kf = *(const f16x8*)(Kb + (f * 16 + lq) * 128 + co);
                s[f] = __builtin_amdgcn_mfma_f32_16x16x32_f16(kf, qf[kk], s[f], 0, 0, 0);
            }
        __builtin_amdgcn_s_setprio(0);

        const u64 wsh = cm >> (lg * 4);
        const unsigned lo = (unsigned)wsh, hi = (unsigned)(wsh >> 32);
        f16x4 ph[4];
        #pragma unroll
        for (int f = 0; f < 4; ++f) {
            const unsigned nib = ((f < 2) ? (lo >> (f * 16)) : (hi >> ((f - 2) * 16))) & 0xFu;
            #pragma unroll
            for (int r = 0; r < 4; ++r)
                if (nib & (1u << r)) s[f][r] = -1e18f;
            const float p0 = __builtin_amdgcn_exp2f(s[f][0]);
            const float p1 = __builtin_amdgcn_exp2f(s[f][1]);
            const float p2 = __builtin_amdgcn_exp2f(s[f][2]);
            const float p3 = __builtin_amdgcn_exp2f(s[f][3]);
            lsum += (p0 + p1) + (p2 + p3);
            f16x2 pa = __builtin_bit_cast(f16x2, __builtin_amdgcn_cvt_pkrtz(p0, p1));
            f16x2 pb = __builtin_bit_cast(f16x2, __builtin_amdgcn_cvt_pkrtz(p2, p3));
            ph[f][0] = pa[0]; ph[f][1] = pa[1]; ph[f][2] = pb[0]; ph[f][3] = pb[1];
        }

        if (topblk) {
            if (TOPF16) {
                f16* T = (f16*)topout;
                #pragma unroll
                for (int f = 0; f < 4; ++f)
                    *(f16x4*)(T + ((size_t)b * LL + qrow) * LL + kt * 64 + f * 16 + lg * 4) = ph[f];
            } else {
                float* T = (float*)topout;
                #pragma unroll
                for (int f = 0; f < 4; ++f)
                    *(f32x4*)(T + ((size_t)b * LL + qrow) * LL + kt * 64 + f * 16 + lg * 4) = s[f];
            }
        }

        #pragma unroll
        for (int f = 0; f < 4; ++f) {
            const int chunk = f * 2 + (lg >> 1);
            const int bo = ((chunk ^ (lq & 7)) << 4) + (lg & 1) * 8;
            *(f16x4*)(lds + (wid << 11) + lq * 128 + bo) = ph[f];
        }

        __builtin_amdgcn_s_setprio(1);
        #pragma unroll
        for (int kk = 0; kk < 2; ++kk) {
            const int co = (((kk * 4 + lg) ^ (lq & 7)) << 4);
            f16x8 pf = *(const f16x8*)(lds + (wid << 11) + lq * 128 + co);
            #pragma unroll
            for (int f = 0; f < 4; ++f) {
                f16x8 vf = *(const f16x8*)(Vb + (f * 16 + lq) * 128 + co);
                acc[f] = __builtin_amdgcn_mfma_f32_16x16x32_f16(vf, pf, acc[f], 0, 0, 0);
            }
        }
        __builtin_amdgcn_s_setprio(0);
    }

    lsum += __shfl_xor(lsum, 16);
    lsum += __shfl_xor(lsum, 32);
    const float linv = 1.f / lsum;
    #pragma unroll
    for (int f = 0; f < 4; ++f) {
        f16x4 ov;
        #pragma unroll
        for (int r = 0; r < 4; ++r) ov[r] = (f16)(acc[f][r] * linv);
        *(f16x4*)(Op + (size_t)(b * LL + qrow) * DD + h * 64 + f * 16 + lg * 4) = ov;
    }
    if (topblk && lg == 0) statsLinv[(size_t)b * LL + qrow] = linv;
}

// ---------------- launch ----------------
extern "C" void kernel_launch(void* const* d_in, const int* in_sizes, int n_in,
                              void* d_out, int out_size, void* d_ws, size_t ws_size,
                              hipStream_t stream) {
    const float* q   = (const float*)d_in[0];
    const float* k   = (const float*)d_in[1];
    const float* v   = (const float*)d_in[2];
    const int*   msk = (const int*)d_in[3];
    const float* wq  = (const float*)d_in[4];
    const float* wk  = (const float*)d_in[5];
    const float* wv  = (const float*)d_in[6];
    const float* wo  = (const float*)d_in[7];
    float* out = (float*)d_out;

    const size_t NX = (size_t)BB * LL * DD;
    const size_t NW = (size_t)DD * DD;
    const int NMW = BB * LL * (LL / 64);
    const size_t NXo = NX;
    const float SCQ = 0.125f * 1.4426950408889634f;
    const int ALDS = 40960;

    f16* ws = (f16*)d_ws;
    const size_t needed = (6 * NX + 4 * NW) * 2 + (size_t)NMW * 8 + (size_t)BB * LL * 4;
    const bool fused = ws_size >= needed;

    if (fused) {
        f16* Op   = ws;
        f16* wh   = Op + NX;
        f16* wqh = wh, *wkh = wh + NW, *wvh = wh + 2 * NW, *woh = wh + 3 * NW;
        f16* Qp  = wh + 4 * NW;
        f16* Kp  = Qp + NX;
        f16* VTp = Kp + NX;
        f16* topP = VTp + NX;
        u64* Mp  = (u64*)(topP + 2 * NX);
        float* statsLinv = (float*)(Mp + NMW);

        prep<<<dim3(1024, 2), 256, 0, stream>>>(msk, wq, wk, wv, wo, wh, Mp);
        gemm_qkv<<<768, 256, 0, stream>>>(q, k, v, wqh, wkh, wvh, Qp, Kp, VTp, SCQ);
        attn_fwd<true><<<1024, 256, ALDS, stream>>>(Qp, Kp, VTp, Mp, Op, topP, statsLinv);
        finale<true><<<1536, 256, 0, stream>>>(Op, woh, out, out + NXo, topP, statsLinv);
    } else {
        f16* bufA = ws;
        f16* wh   = bufA + NX;
        f16* wqh = wh, *wkh = wh + NW, *wvh = wh + 2 * NW, *woh = wh + 3 * NW;
        f16* Qp  = wh + 4 * NW;
        f16* Kp  = Qp + NX;
        f16* VTp = Kp + NX;
        u64* Mp  = (u64*)(VTp + NX);
        float* statsLinv = (float*)(Mp + NMW);

        pack_mask<<<256, 256, 0, stream>>>(msk, Mp, NMW);
        cvt4_kernel<<<dim3(128, 4), 256, 0, stream>>>(wq, wk, wv, wo, wh, (int)(NW / 4));
        cvt_kernel<<<2048, 256, 0, stream>>>(q, bufA, (int)(NX / 4), SCQ);
        gemm_one<<<dim3(8, 32), 256, 0, stream>>>(bufA, wqh, Qp, 0);
        cvt_kernel<<<2048, 256, 0, stream>>>(k, bufA, (int)(NX / 4), 1.f);
        gemm_one<<<dim3(8, 32), 256, 0, stream>>>(bufA, wkh, Kp, 1);
        cvt_kernel<<<2048, 256, 0, stream>>>(v, bufA, (int)(NX / 4), 1.f);
        gemm_one<<<dim3(8, 32), 256, 0, stream>>>(bufA, wvh, VTp, 2);
        attn_fwd<false><<<1024, 256, ALDS, stream>>>(Qp, Kp, VTp, Mp, bufA,
                                                     out + NXo, statsLinv);
        finale<false><<<1536, 256, 0, stream>>>(bufA, woh, out, out + NXo, out + NXo, statsLinv);
    }
}